// Round 5
// baseline (358.042 us; speedup 1.0000x reference)
//
#include <hip/hip_runtime.h>
#include <math.h>

// Fused CNN classifier: conv(1->8,3x3,s2,p1)+ReLU -> conv(8->16,3x3,s2,p1)+ReLU
//                       -> FC(784->1) -> softplus+0.001 -> 1-exp(-r) -> clip
// B=65536 images of 1x28x28 fp32.
//
// R7 (4th resubmit — R1-R4 benches were GPUAcquisitionTimeouts, no data):
// barrier-free restructure. R6 was stall-bound (VALU 53%, MFMA 3%, HBM 8%):
// 2 syncthreads/q-iter forced 4-wave lockstep with staging HBM latency inside
// the critical path, and staging/conv1 address math (magic divides) was
// recomputed every iteration. Fix:
//  - each wave stages ITS OWN image (still coalesced: 196 consecutive float4
//    over 64 lanes) -> simg/sz1 strictly wave-private -> NO barriers at all.
//  - software prefetch: next image's 4 float4 loaded into regs right after
//    the LDS write, consumed next iteration (HBM latency hidden under conv).
//  - all addressing hoisted to init (src4/dstf/wboff/zoff).
//  - simg geometry 29 rows x 36 stride, data col c at offset c+4: staging
//    writes are 16B-aligned ds_write_b128 (1 instr, conflict-free tiling).
//  - z1 pack via v_cvt_pk_bf16_f32 (1 instr per 2 channels, RNE like f2bf).
// conv2 (MFMA path) unchanged from R6: A = z1 im2col (one ds_read_b128/frag),
// B = W2 bf16 in registers, k >= 72 zeroed on B side.

typedef short bf16x8 __attribute__((ext_vector_type(8)));
typedef float f32x4  __attribute__((ext_vector_type(4)));

#define NBLOCKS 4096
#define Z1_RS 19                    // z1 row stride in 16B slots (odd!)
#define Z1_SLOTS (15 * Z1_RS)       // 285 slots per image
#define IMG_RS 36                   // simg row stride in floats (16B-aligned rows)
#define IMG_ROWS 29                 // rows -1..27 stored at ro = r+1
#define IMG_FLOATS (IMG_ROWS * IMG_RS)   // 1044 floats = 4176 B

static __device__ __forceinline__ short f2bf(float f) {
    union { float f; unsigned u; } v; v.f = f;
    unsigned r = v.u + 0x7FFF + ((v.u >> 16) & 1);   // RNE (no NaN inputs)
    return (short)(r >> 16);
}

__global__ __launch_bounds__(256, 4) void fused_cnn_mfma(
    const float* __restrict__ x,
    const float* __restrict__ W1, const float* __restrict__ b1,
    const float* __restrict__ W2, const float* __restrict__ b2,
    const float* __restrict__ Wfc, const float* __restrict__ bfc,
    float* __restrict__ out, int nimg)
{
    __shared__ __align__(16) float simg[4][IMG_FLOATS];   // 16704 B
    __shared__ bf16x8 sz1[4][Z1_SLOTS];                   // 18240 B

    const int tid  = threadIdx.x;
    const int w    = tid >> 6;       // wave id = image slot (wave-private LDS)
    const int lane = tid & 63;
    const int hi   = lane >> 4;
    const int lo   = lane & 15;

    // ---------------- one-time setup (all wave-private, no barrier) --------
    {
        f32x4 z4 = {0.f, 0.f, 0.f, 0.f};
        f32x4* sp = (f32x4*)&simg[w][0];
        for (int i = lane; i < IMG_FLOATS / 4; i += 64) sp[i] = z4;
        bf16x8 zz = {0,0,0,0,0,0,0,0};
        for (int i = lane; i < Z1_SLOTS; i += 64) sz1[w][i] = zz;
    }

    // B-frags: W2 as bf16 in registers. k = tap*8 + ic; lane(hi,lo):
    // B[k=kk*32+hi*8+j][n=lo] -> tap = kk*4+hi, ic=j. tap>=9 => 0 (K-pad).
    bf16x8 wb[3];
    #pragma unroll
    for (int kk = 0; kk < 3; kk++) {
        const int tap = kk * 4 + hi;
        #pragma unroll
        for (int j = 0; j < 8; j++)
            wb[kk][j] = (tap < 9) ? f2bf(W2[lo * 72 + j * 9 + tap])
                                  : (short)0;
    }

    // conv2 A-read byte offsets into sz1[w]: slot = (2qy+ty)*19 + (2qx+tx)
    int posoff[4];
    #pragma unroll
    for (int t = 0; t < 4; t++) {
        int p = t * 16 + lo; if (p > 48) p = 48;
        int qy = p / 7, qx = p - qy * 7;
        posoff[t] = ((2 * qy) * Z1_RS + 2 * qx) * 16;
    }
    int tapoff[3];
    #pragma unroll
    for (int kk = 0; kk < 3; kk++) {
        int tap = kk * 4 + hi;
        int ty = tap / 3, tx = tap - ty * 3;
        tapoff[kk] = (tap < 9) ? (ty * Z1_RS + tx) * 16 : 0;
    }

    // Staging constants: per j, float4 index in image + dst float offset.
    int src4[4], dstf[4];
    #pragma unroll
    for (int j = 0; j < 4; j++) {
        int p4 = j * 64 + lane; if (p4 > 195) p4 = 195;
        int yy = p4 / 7, xq = p4 - yy * 7;
        src4[j] = p4;
        dstf[j] = (yy + 1) * IMG_RS + 4 + 4 * xq;   // 16B-aligned
    }

    // conv1 constants: per i, read base offset + z1 write byte offset.
    int wboff[4], zoff[4];
    #pragma unroll
    for (int i = 0; i < 4; i++) {
        int p = i * 64 + lane; if (p > 195) p = 195;
        int py = p / 14, px = p - py * 14;
        wboff[i] = (2 * py) * IMG_RS + 2 * px + 3;
        zoff[i]  = ((py + 1) * Z1_RS + px + 1) * 16;
    }

    // Epilogue constants: lane(hi,lo) holds D[pos=t*16+hi*4+r][c2=lo].
    const float b2v = b2[lo];
    float wfc[4][4];
    #pragma unroll
    for (int t = 0; t < 4; t++)
        #pragma unroll
        for (int r = 0; r < 4; r++) {
            int p = t * 16 + hi * 4 + r;
            wfc[t][r] = (p < 49) ? Wfc[lo * 49 + p] : 0.f;
        }
    const float bfc0 = bfc[0];

    const int nquad = (nimg + 3) >> 2;
    float* const sw = &simg[w][0];
    char* const z1b = (char*)&sz1[w][0];

    // ---- prologue prefetch: image for q = blockIdx.x ----
    float4 pf[4];
    {
        int img = blockIdx.x * 4 + w;
        if (img >= nimg) img = nimg - 1;
        const float4* sp = (const float4*)(x + (size_t)img * 784);
        #pragma unroll
        for (int j = 0; j < 4; j++) pf[j] = sp[src4[j]];
    }

    for (int q = blockIdx.x; q < nquad; q += gridDim.x) {
        // ---- write prefetched image to LDS (wave-private, aligned b128) ----
        *(float4*)(sw + dstf[0]) = pf[0];
        *(float4*)(sw + dstf[1]) = pf[1];
        *(float4*)(sw + dstf[2]) = pf[2];
        if (lane < 4) *(float4*)(sw + dstf[3]) = pf[3];

        // ---- issue next image's loads; they complete under conv1+conv2 ----
        {
            int qn = q + gridDim.x;
            if (qn < nquad) {
                int imgn = qn * 4 + w;
                if (imgn >= nimg) imgn = nimg - 1;
                const float4* sp = (const float4*)(x + (size_t)imgn * 784);
                #pragma unroll
                for (int j = 0; j < 4; j++) pf[j] = sp[src4[j]];
            }
        }

        // ---- conv1 (fp32 VALU); write z1 bf16x8 via v_cvt_pk_bf16_f32 ----
        #pragma unroll
        for (int i = 0; i < 4; i++) {
            const float* wbse = sw + wboff[i];
            float t0 = wbse[0],            t1 = wbse[1],            t2 = wbse[2];
            float t3 = wbse[IMG_RS],       t4 = wbse[IMG_RS + 1],   t5 = wbse[IMG_RS + 2];
            float t6 = wbse[2 * IMG_RS],   t7 = wbse[2 * IMG_RS + 1], t8 = wbse[2 * IMG_RS + 2];
            asm volatile("" : "+v"(t0), "+v"(t1), "+v"(t2), "+v"(t3), "+v"(t4),
                              "+v"(t5), "+v"(t6), "+v"(t7), "+v"(t8));
            union { bf16x8 v; unsigned u[4]; } zz;
            #pragma unroll
            for (int c = 0; c < 8; c += 2) {
                const float* wa = &W1[c * 9];
                const float* wc = &W1[(c + 1) * 9];
                float za = b1[c], zc = b1[c + 1];
                za = fmaf(t0, wa[0], za); zc = fmaf(t0, wc[0], zc);
                za = fmaf(t1, wa[1], za); zc = fmaf(t1, wc[1], zc);
                za = fmaf(t2, wa[2], za); zc = fmaf(t2, wc[2], zc);
                za = fmaf(t3, wa[3], za); zc = fmaf(t3, wc[3], zc);
                za = fmaf(t4, wa[4], za); zc = fmaf(t4, wc[4], zc);
                za = fmaf(t5, wa[5], za); zc = fmaf(t5, wc[5], zc);
                za = fmaf(t6, wa[6], za); zc = fmaf(t6, wc[6], zc);
                za = fmaf(t7, wa[7], za); zc = fmaf(t7, wc[7], zc);
                za = fmaf(t8, wa[8], za); zc = fmaf(t8, wc[8], zc);
                za = fmaxf(za, 0.f);      zc = fmaxf(zc, 0.f);
                unsigned pk;
                asm("v_cvt_pk_bf16_f32 %0, %1, %2" : "=v"(pk) : "v"(za), "v"(zc));
                zz.u[c >> 1] = pk;
            }
            if (i < 3 || lane < 4) *(bf16x8*)(z1b + zoff[i]) = zz.v;
        }

        // ---- conv2: 4 pos-tiles x 3 K-steps; A = z1 (one b128/frag) ----
        f32x4 acc[4];
        {
            f32x4 z4 = {0.f, 0.f, 0.f, 0.f};
            #pragma unroll
            for (int t = 0; t < 4; t++) acc[t] = z4;
        }
        #pragma unroll
        for (int t = 0; t < 4; t++) {
            #pragma unroll
            for (int kk = 0; kk < 3; kk++) {
                bf16x8 af = *(const bf16x8*)(z1b + posoff[t] + tapoff[kk]);
                acc[t] = __builtin_amdgcn_mfma_f32_16x16x32_bf16(
                             af, wb[kk], acc[t], 0, 0, 0);
            }
        }

        // ---- epilogue: bias+ReLU+FC fold, wave reduce, softplus ----
        float fc = 0.f;
        #pragma unroll
        for (int t = 0; t < 4; t++)
            #pragma unroll
            for (int r = 0; r < 4; r++) {
                float z = fmaxf(acc[t][r] + b2v, 0.f);
                fc = fmaf(z, wfc[t][r], fc);
            }
        #pragma unroll
        for (int off = 32; off > 0; off >>= 1)
            fc += __shfl_down(fc, off, 64);

        if (lane == 0) {
            int img = q * 4 + w;
            if (img < nimg) {
                float v    = fc + bfc0;
                float sp   = fmaxf(v, 0.f) + log1pf(expf(-fabsf(v)));
                float rate = sp + 0.001f;
                float pr   = 1.f - expf(-rate);
                out[img] = fminf(fmaxf(pr, 1e-6f), 1.f - 1e-6f);
            }
        }
    }
}

extern "C" void kernel_launch(void* const* d_in, const int* in_sizes, int n_in,
                              void* d_out, int out_size, void* d_ws, size_t ws_size,
                              hipStream_t stream) {
    const float* x   = (const float*)d_in[0];
    const float* W1  = (const float*)d_in[1];
    const float* b1  = (const float*)d_in[2];
    const float* W2  = (const float*)d_in[3];
    const float* b2  = (const float*)d_in[4];
    const float* Wfc = (const float*)d_in[5];
    const float* bfc = (const float*)d_in[6];
    float* out = (float*)d_out;

    const int nimg  = in_sizes[0] / 784;
    const int nquad = (nimg + 3) / 4;
    const int grid  = nquad < NBLOCKS ? nquad : NBLOCKS;

    fused_cnn_mfma<<<grid, 256, 0, stream>>>(x, W1, b1, W2, b2, Wfc, bfc,
                                             out, nimg);
}